// Round 5
// baseline (232.776 us; speedup 1.0000x reference)
//
#include <hip/hip_runtime.h>
#include <math.h>

#define N_PIX 65536
#define EPSF 1e-6f
#define CHUNKS 32
#define PX_PER_CHUNK 2048
#define PX_PER_WAVE 512     // 4 waves per block, 8 super-tiles of 64 px
#define N_TILES (PX_PER_WAVE / 64)
#define N_JOBS 48           // 2 imgs * 8 batch * 3 channels
#define N_BLOCKS (N_JOBS * CHUNKS)   // 1536
#define SLOTS 4             // per-job accumulator copies (8-way atomic sharing)
#define N_RBLOCKS (24 * 4)  // 96 reduce blocks
#define LN2_50 34.65735903f // 50 * ln(2): log2 -> scaled-ln

typedef __attribute__((ext_vector_type(2))) float f2;
using short8 = __attribute__((ext_vector_type(8))) short;
using f32x4  = __attribute__((ext_vector_type(4))) float;

__device__ __forceinline__ float rcp_fast(float x) { return __builtin_amdgcn_rcpf(x); }

#if __has_builtin(__builtin_amdgcn_cvt_pk_bf16_f32)
typedef __attribute__((ext_vector_type(2))) __bf16 bf16x2_t;
__device__ __forceinline__ uint32_t pk_bf16(float a, float b) {
    return __builtin_bit_cast(uint32_t, __builtin_amdgcn_cvt_pk_bf16_f32(a, b));
}
#else
// fallback: round-half-up (inputs positive finite), 3 ops
__device__ __forceinline__ uint32_t pk_bf16(float a, float b) {
    const uint32_t ua = __builtin_bit_cast(uint32_t, a) + 0x8000u;
    const uint32_t ub = __builtin_bit_cast(uint32_t, b) + 0x8000u;
    return __builtin_amdgcn_perm(ub, ua, 0x07060302u);
}
#endif

// phase A: pixel -> (u*50, v*50, weight); log2-based (ln2 folded into scale)
__device__ __forceinline__ float4 phaseA(float pr, float pg, float pb, int c) {
    const float r  = pr + EPSF;
    const float g  = pg + EPSF;
    const float bl = pb + EPSF;
    const float wgt = sqrtf(fmaf(r, r, fmaf(g, g, bl * bl)));
    const float lr = __log2f(r), lg = __log2f(g), lb2 = __log2f(bl);
    // channel c: u = l_c - l_a, v = l_c - l_b;  c0:(a,b)=(g,b) c1:(r,b) c2:(r,g)
    const float l0 = (c == 0) ? lr : ((c == 1) ? lg : lb2);
    const float lu = (c == 0) ? lg : lr;
    const float lv = (c == 2) ? lg : lb2;
    return make_float4((l0 - lu) * LN2_50, (l0 - lv) * LN2_50, wgt, 0.0f);
}

// ---------------------------------------------------------------------------
// Kernel 1 (R5): hist core = R19 verbatim (proven 89us); epilogue now
// atomicAdds into SLOTS=4 per-job accumulators instead of storing 32
// per-chunk partials.
// R4 post-mortem: fused ticketed reduction regressed hist 89->166us. The
// per-block ACQ_REL/AGENT atomics (1536 release L2-writebacks + 1536
// acquire L1/L2-invalidates, one every ~100ns) destroyed cross-block L2/L3
// input reuse (FETCH +13MB) and stalled in-flight loads chip-wide; plus 24
// co-resident 1MB latency-bound reducers. Device-scope acq_rel per block is
// a chip-wide cache hazard. REVERTED to two dispatches.
// R5 change: plain device-scope f32 atomicAdd (no ordering semantics -> no
// cache flushes; m20) folds the 32-chunk sum into k1. Footprint k2 must
// read: 25.2MB -> 3.1MB (48 jobs x 4 slots x 16KB); k1 sheds ~100MB of HBM
// partial-store traffic. slot=chunk&3: adjacent-in-time blocks hit
// different slots; 8-way element sharing, 6.3M atomic-f32 spread over 89us.
// Hist structure notes (R19, unchanged): barrier-free wave-private phases
// ARE the latency-hiding (R2: block-barrier convoying loses 12%); one v_rcp
// per denominator; fragment-direct operand gen; wave-strip element order is
// a job-independent bijection so elementwise k2 reduce is exact.
// ---------------------------------------------------------------------------
__global__ __launch_bounds__(256, 4) void hist_kernel(
    const float* __restrict__ x, const float* __restrict__ y,
    float* __restrict__ jobacc, float* __restrict__ accum)
{
    const int blk = blockIdx.x;            // 0..1535
    const int chunk = blk & (CHUNKS - 1);
    const int job = blk / CHUNKS;          // 0..47 (img*24 + b*3 + c)
    const int c = job % 3;
    const int ib = job / 3;                // img*8 + b
    const int img = ib >> 3;
    const int b = ib & 7;
    const float* __restrict__ src = (img == 0 ? x : y) + (size_t)b * 3 * N_PIX;

    const int tid = threadIdx.x;

    __shared__ __align__(16) float lds[4096];   // 16 KB: wbufs / epilogue strips
    const int lane = tid & 63;
    const int wv = tid >> 6;
    float* __restrict__ wbuf = lds + wv * 288;  // 64 px * float4, +16B pad per 8 px

    const int quad = lane >> 4;
    const int l15 = lane & 15;
    // negated scaled centers for this lane's 4 m-rows: -(c_m * 50), m = mt*16+l15
    f2 ncb01, ncb23;
    {
        const float c0 = (-3.0f + (float)(l15)      * (6.0f / 63.0f)) * 50.0f;
        const float c1 = (-3.0f + (float)(16 + l15) * (6.0f / 63.0f)) * 50.0f;
        const float c2 = (-3.0f + (float)(32 + l15) * (6.0f / 63.0f)) * 50.0f;
        const float c3 = (-3.0f + (float)(48 + l15) * (6.0f / 63.0f)) * 50.0f;
        ncb01 = (f2){-c0, -c1};
        ncb23 = (f2){-c2, -c3};
    }
    const f2 one2 = {1.0f, 1.0f};

    f32x4 acc[16];                         // acc[mt*4+nt]
#pragma unroll
    for (int i = 0; i < 16; ++i) acc[i] = (f32x4){0.f, 0.f, 0.f, 0.f};

    const int px0 = chunk * PX_PER_CHUNK + wv * PX_PER_WAVE;

    // prefetch super-tile 0
    float pr, pg, pb;
    {
        const int n = px0 + lane;
        pr = src[n]; pg = src[N_PIX + n]; pb = src[2 * N_PIX + n];
    }

#pragma unroll 1
    for (int st = 0; st < N_TILES; ++st) {
        // ---- Phase A: one pixel per lane; stage to LDS (same-wave, in-order) ----
        const float4 uvw = phaseA(pr, pg, pb, c);
        *(float4*)(wbuf + lane * 4 + (lane >> 3) * 4) = uvw;

        if (st + 1 < N_TILES) {            // prefetch next tile's raw pixels
            const int n2 = px0 + (st + 1) * 64 + lane;
            pr = src[n2]; pg = src[N_PIX + n2]; pb = src[2 * N_PIX + n2];
        }

#pragma unroll
        for (int h = 0; h < 2; ++h) {              // two K=32 halves
            const int base = h * 32 + quad * 8;    // first pixel this lane consumes
            const float4* __restrict__ pbase =
                (const float4*)(wbuf + base * 4 + (base >> 3) * 4);
            int aU[4][4], aV[4][4];                // fragment words [mt][jp]

#pragma unroll
            for (int jp = 0; jp < 4; ++jp) {       // j = 2jp (even), 2jp+1 (odd)
                const float4 pe = pbase[2 * jp];
                const float4 po = pbase[2 * jp + 1];

                f2 aue01, aue23, auo01, auo23;
                f2 bve01, bve23, bvo01, bvo23;
#pragma unroll
                for (int eo = 0; eo < 2; ++eo) {
                    const float ru = eo ? po.x : pe.x;
                    const float rv = eo ? po.y : pe.y;
                    const float rw = eo ? po.z : pe.z;
                    const f2 ru2 = {ru, ru}, rv2 = {rv, rv}, rw2 = {rw, rw};
                    const f2 tu01 = ru2 + ncb01, tu23 = ru2 + ncb23;
                    const f2 tv01 = rv2 + ncb01, tv23 = rv2 + ncb23;
                    const f2 qu01 = __builtin_elementwise_fma(tu01, tu01, one2);
                    const f2 qu23 = __builtin_elementwise_fma(tu23, tu23, one2);
                    const f2 qv01 = __builtin_elementwise_fma(tv01, tv01, one2);
                    const f2 qv23 = __builtin_elementwise_fma(tv23, tv23, one2);
                    // one rcp per denominator: trans pipe co-issues with VALU;
                    // V needs ZERO multiplies (rcp is the value), U just *w.
                    const f2 au01 = (f2){rcp_fast(qu01.x), rcp_fast(qu01.y)} * rw2;
                    const f2 au23 = (f2){rcp_fast(qu23.x), rcp_fast(qu23.y)} * rw2;
                    const f2 bv01 = {rcp_fast(qv01.x), rcp_fast(qv01.y)};
                    const f2 bv23 = {rcp_fast(qv23.x), rcp_fast(qv23.y)};
                    if (eo) { auo01 = au01; auo23 = au23; bvo01 = bv01; bvo23 = bv23; }
                    else    { aue01 = au01; aue23 = au23; bve01 = bv01; bve23 = bv23; }
                }
                aU[0][jp] = pk_bf16(aue01.x, auo01.x);   // mt0 <- center c0
                aU[1][jp] = pk_bf16(aue01.y, auo01.y);   // mt1 <- c1
                aU[2][jp] = pk_bf16(aue23.x, auo23.x);   // mt2 <- c2
                aU[3][jp] = pk_bf16(aue23.y, auo23.y);   // mt3 <- c3
                aV[0][jp] = pk_bf16(bve01.x, bvo01.x);
                aV[1][jp] = pk_bf16(bve01.y, bvo01.y);
                aV[2][jp] = pk_bf16(bve23.x, bvo23.x);
                aV[3][jp] = pk_bf16(bve23.y, bvo23.y);
            }

            short8 af[4], bf[4];
#pragma unroll
            for (int mt = 0; mt < 4; ++mt) {
                af[mt] = __builtin_bit_cast(short8,
                    make_int4(aU[mt][0], aU[mt][1], aU[mt][2], aU[mt][3]));
                bf[mt] = __builtin_bit_cast(short8,
                    make_int4(aV[mt][0], aV[mt][1], aV[mt][2], aV[mt][3]));
            }
#pragma unroll
            for (int mt = 0; mt < 4; ++mt)
#pragma unroll
                for (int nt = 0; nt < 4; ++nt)
                    acc[mt * 4 + nt] = __builtin_amdgcn_mfma_f32_16x16x32_bf16(
                        af[mt], bf[nt], acc[mt * 4 + nt], 0, 0, 0);
        }
    }

    // ---- Epilogue: 4 chunks over mt; LDS cross-wave reduce (linear b128),
    // then 4 scalar f32 atomicAdds into the (job, chunk&3) slot accumulator.
    // Plain device-scope atomics: no fences, no cache writeback/invalidate.
    float* __restrict__ outp =
        jobacc + ((size_t)job * SLOTS + (chunk & (SLOTS - 1))) * 4096;
#pragma unroll 1
    for (int ch = 0; ch < 4; ++ch) {
        __syncthreads();                   // previous chunk (or main loop) done
#pragma unroll
        for (int nt = 0; nt < 4; ++nt)     // wave strip: [wv][nt*256 + lane*4 + i]
            *(f32x4*)(lds + wv * 1024 + nt * 256 + lane * 4) = acc[ch * 4 + nt];
        __syncthreads();
        const int e4 = tid * 4;            // 0..1023, linear -> conflict-free b128
        const f32x4 s0 = *(const f32x4*)(lds +        e4);
        const f32x4 s1 = *(const f32x4*)(lds + 1024 + e4);
        const f32x4 s2 = *(const f32x4*)(lds + 2048 + e4);
        const f32x4 s3 = *(const f32x4*)(lds + 3072 + e4);
        const f32x4 s = (s0 + s1) + (s2 + s3);
        float* __restrict__ dst = outp + ch * 1024 + e4;
        atomicAdd(dst + 0, s.x);
        atomicAdd(dst + 1, s.y);
        atomicAdd(dst + 2, s.z);
        atomicAdd(dst + 3, s.w);
    }
}

// ---------------------------------------------------------------------------
// Kernel 2 (R5): Bhattacharyya-factored reduction + fused finalize over the
// 3.1MB slot accumulators (was 25.2MB chunk partials -> latency-bound 40-50us;
// now 8 f32x4 loads/thread ~ 2 memory round-trips, ~5-8us).
//   sum (sqrt(y/TY)-sqrt(x/TX))^2 = 2(1 - rho), rho = sum sqrt(sx*sy)/sqrt(TX*TY)
// 96 blocks x 256 (24 x-jobs x 4 slices): each thread owns one element-QUAD;
// sums the 4 slots for x and y, then sx=Σqx, sy=Σqy, cr=Σ sqrt(qx*qy).
// Block-reduce 3 scalars, 3 device atomicAdds; tid0 RELEASE-ticket; the
// 96th block ACQUIRE-loads accum and writes out[0]. (Proven R0 machinery.)
// ---------------------------------------------------------------------------
__global__ __launch_bounds__(256) void reduce_cross_kernel(
    const float* __restrict__ jobacc, float* __restrict__ accum,
    float* __restrict__ out)
{
    unsigned* __restrict__ ticket = (unsigned*)(accum + 24);
    const int jx = blockIdx.x >> 2;                        // 0..23 (img0 job)
    const int bb = jx / 3;                                 // batch 0..7
    const int e4 = (((blockIdx.x & 3) << 8) | threadIdx.x) * 4;  // 0..4092
    const float* px = jobacc + (size_t)jx * SLOTS * 4096 + e4;
    const float* py = jobacc + (size_t)(24 + jx) * SLOTS * 4096 + e4;

    f32x4 qx = {0.f, 0.f, 0.f, 0.f}, qy = {0.f, 0.f, 0.f, 0.f};
#pragma unroll
    for (int s = 0; s < SLOTS; ++s) {
        qx += *(const f32x4*)(px + (size_t)s * 4096);
        qy += *(const f32x4*)(py + (size_t)s * 4096);
    }
    float sx = (qx.x + qx.y) + (qx.z + qx.w);
    float sy = (qy.x + qy.y) + (qy.z + qy.w);
    float cr = (sqrtf(qx.x * qy.x) + sqrtf(qx.y * qy.y)) +
               (sqrtf(qx.z * qy.z) + sqrtf(qx.w * qy.w));

#pragma unroll
    for (int o = 32; o > 0; o >>= 1) {
        sx += __shfl_down(sx, o, 64);
        sy += __shfl_down(sy, o, 64);
        cr += __shfl_down(cr, o, 64);
    }
    __shared__ float red[12];
    const int wv = threadIdx.x >> 6;
    if ((threadIdx.x & 63) == 0) {
        red[wv] = sx; red[4 + wv] = sy; red[8 + wv] = cr;
    }
    __syncthreads();
    if (threadIdx.x == 0) {
        atomicAdd(&accum[bb],      red[0] + red[1] + red[2] + red[3]);
        atomicAdd(&accum[8 + bb],  red[4] + red[5] + red[6] + red[7]);
        atomicAdd(&accum[16 + bb], red[8] + red[9] + red[10] + red[11]);
        const unsigned old = __hip_atomic_fetch_add(ticket, 1u,
                                 __ATOMIC_ACQ_REL, __HIP_MEMORY_SCOPE_AGENT);
        if (old == N_RBLOCKS - 1) {        // last arriver: all atomicAdds visible
            float s = 0.0f;
#pragma unroll
            for (int b = 0; b < 8; ++b) {
                const float tx = __hip_atomic_load(&accum[b],      __ATOMIC_ACQUIRE, __HIP_MEMORY_SCOPE_AGENT);
                const float ty = __hip_atomic_load(&accum[8 + b],  __ATOMIC_ACQUIRE, __HIP_MEMORY_SCOPE_AGENT);
                const float cc = __hip_atomic_load(&accum[16 + b], __ATOMIC_ACQUIRE, __HIP_MEMORY_SCOPE_AGENT);
                const float rho = cc * __builtin_amdgcn_rsqf(tx * ty);
                s += sqrtf(fmaxf(1.0f - rho, 0.0f));
            }
            out[0] = s * 0.125f;
        }
    }
}

extern "C" void kernel_launch(void* const* d_in, const int* in_sizes, int n_in,
                              void* d_out, int out_size, void* d_ws, size_t ws_size,
                              hipStream_t stream)
{
    const float* x = (const float*)d_in[0];
    const float* y = (const float*)d_in[1];
    float* ws = (float*)d_ws;
    float* jobacc = ws;                                   // 48*4*4096 floats (3.1 MB)
    float* accum = ws + (size_t)N_JOBS * SLOTS * 4096;    // 24 sums + ticket
    float* outf = (float*)d_out;

    // zero slot accumulators + accum/ticket (graph-capturable, stream-ordered)
    hipMemsetAsync(ws, 0, ((size_t)N_JOBS * SLOTS * 4096 + 25) * sizeof(float),
                   stream);
    hipLaunchKernelGGL(hist_kernel, dim3(N_BLOCKS), dim3(256), 0, stream,
                       x, y, jobacc, accum);
    hipLaunchKernelGGL(reduce_cross_kernel, dim3(N_RBLOCKS), dim3(256), 0, stream,
                       jobacc, accum, outf);
}

// Round 6
// 152.309 us; speedup vs baseline: 1.5283x; 1.5283x over previous
//
#include <hip/hip_runtime.h>
#include <math.h>

#define N_PIX 65536
#define EPSF 1e-6f
#define CHUNKS 16           // R6: halved (was 32) — 768 blocks, 3/CU exact balance
#define PX_PER_CHUNK 4096   // 65536 / 16
#define PX_PER_WAVE 1024    // 4 waves per block, 16 super-tiles of 64 px
#define N_TILES (PX_PER_WAVE / 64)
#define N_JOBS 48           // 2 imgs * 8 batch * 3 channels
#define N_BLOCKS (N_JOBS * CHUNKS)   // 768
#define N_RBLOCKS (24 * 4)           // 96 reduce blocks (f32x4 per thread)
#define LN2_50 34.65735903f // 50 * ln(2): log2 -> scaled-ln

typedef __attribute__((ext_vector_type(2))) float f2;
using short8 = __attribute__((ext_vector_type(8))) short;
using f32x4  = __attribute__((ext_vector_type(4))) float;

__device__ __forceinline__ float rcp_fast(float x) { return __builtin_amdgcn_rcpf(x); }

#if __has_builtin(__builtin_amdgcn_cvt_pk_bf16_f32)
typedef __attribute__((ext_vector_type(2))) __bf16 bf16x2_t;
__device__ __forceinline__ uint32_t pk_bf16(float a, float b) {
    return __builtin_bit_cast(uint32_t, __builtin_amdgcn_cvt_pk_bf16_f32(a, b));
}
#else
// fallback: round-half-up (inputs positive finite), 3 ops
__device__ __forceinline__ uint32_t pk_bf16(float a, float b) {
    const uint32_t ua = __builtin_bit_cast(uint32_t, a) + 0x8000u;
    const uint32_t ub = __builtin_bit_cast(uint32_t, b) + 0x8000u;
    return __builtin_amdgcn_perm(ub, ua, 0x07060302u);
}
#endif

// phase A: pixel -> (u*50, v*50, weight); log2-based (ln2 folded into scale)
__device__ __forceinline__ float4 phaseA(float pr, float pg, float pb, int c) {
    const float r  = pr + EPSF;
    const float g  = pg + EPSF;
    const float bl = pb + EPSF;
    const float wgt = sqrtf(fmaf(r, r, fmaf(g, g, bl * bl)));
    const float lr = __log2f(r), lg = __log2f(g), lb2 = __log2f(bl);
    // channel c: u = l_c - l_a, v = l_c - l_b;  c0:(a,b)=(g,b) c1:(r,b) c2:(r,g)
    const float l0 = (c == 0) ? lr : ((c == 1) ? lg : lb2);
    const float lu = (c == 0) ? lg : lr;
    const float lv = (c == 2) ? lg : lb2;
    return make_float4((l0 - lu) * LN2_50, (l0 - lv) * LN2_50, wgt, 0.0f);
}

// ---------------------------------------------------------------------------
// Kernel 1 (R6): R19/R0 core VERBATIM (proven 89us, VALUBusy 65%), with
// CHUNKS 32->16: 768 blocks of 4096 px. Per-CU work identical and now
// EXACTLY balanced (3 blocks/CU x 2x work = 6 work-units/CU, same as
// 1536/256); partial buffer and k1 store traffic halve; k2 loads halve.
// ATOMIC LEDGER (R4/R5, both reverted): per-block ACQ_REL/AGENT atomics
// (R4) = chip-wide L1/L2 invalidate storm, hist 89->166us; plain f32
// atomicAdd epilogue (R5) = 4B-scatter write-through + cross-XCD line
// ping-pong, WRITE 122->196MB, hist 89->172us. Store-partials + separate
// reduce dispatch is the only epilogue that doesn't poison the caches.
// STRUCTURE LEDGER (R2): block-barrier producer-consumer convoying loses
// 12% even at +33% occupancy — barrier-free wave-private phases ARE the
// latency-hiding mechanism. Phase-B eval: one v_rcp per denominator,
// fully-packed f2 ops; quarter-rate trans pipe co-issues with VALU.
// Contiguous b128 partial stores (wave-strip element order, a
// job-independent bijection => elementwise k2 reduce is exact).
// Block 0 zeroes accum[24]+ticket (only block 0 touches accum in k1).
// ---------------------------------------------------------------------------
__global__ __launch_bounds__(256, 4) void hist_kernel(
    const float* __restrict__ x, const float* __restrict__ y,
    float* __restrict__ partial, float* __restrict__ accum)
{
    const int blk = blockIdx.x;            // 0..767
    const int chunk = blk & (CHUNKS - 1);
    const int job = blk / CHUNKS;          // 0..47
    const int c = job % 3;
    const int ib = job / 3;                // img*8 + b
    const int img = ib >> 3;
    const int b = ib & 7;
    const float* __restrict__ src = (img == 0 ? x : y) + (size_t)b * 3 * N_PIX;

    const int tid = threadIdx.x;
    if (blk == 0 && tid < 25) ((unsigned*)accum)[tid] = 0u;  // accum[24] + ticket

    __shared__ __align__(16) float lds[4096];   // 16 KB: wbufs / epilogue strips
    const int lane = tid & 63;
    const int wv = tid >> 6;
    float* __restrict__ wbuf = lds + wv * 288;  // 64 px * float4, +16B pad per 8 px

    const int quad = lane >> 4;
    const int l15 = lane & 15;
    // negated scaled centers for this lane's 4 m-rows: -(c_m * 50), m = mt*16+l15
    f2 ncb01, ncb23;
    {
        const float c0 = (-3.0f + (float)(l15)      * (6.0f / 63.0f)) * 50.0f;
        const float c1 = (-3.0f + (float)(16 + l15) * (6.0f / 63.0f)) * 50.0f;
        const float c2 = (-3.0f + (float)(32 + l15) * (6.0f / 63.0f)) * 50.0f;
        const float c3 = (-3.0f + (float)(48 + l15) * (6.0f / 63.0f)) * 50.0f;
        ncb01 = (f2){-c0, -c1};
        ncb23 = (f2){-c2, -c3};
    }
    const f2 one2 = {1.0f, 1.0f};

    f32x4 acc[16];                         // acc[mt*4+nt]
#pragma unroll
    for (int i = 0; i < 16; ++i) acc[i] = (f32x4){0.f, 0.f, 0.f, 0.f};

    const int px0 = chunk * PX_PER_CHUNK + wv * PX_PER_WAVE;

    // prefetch super-tile 0
    float pr, pg, pb;
    {
        const int n = px0 + lane;
        pr = src[n]; pg = src[N_PIX + n]; pb = src[2 * N_PIX + n];
    }

#pragma unroll 1
    for (int st = 0; st < N_TILES; ++st) {
        // ---- Phase A: one pixel per lane; stage to LDS (same-wave, in-order) ----
        const float4 uvw = phaseA(pr, pg, pb, c);
        *(float4*)(wbuf + lane * 4 + (lane >> 3) * 4) = uvw;

        if (st + 1 < N_TILES) {            // prefetch next tile's raw pixels
            const int n2 = px0 + (st + 1) * 64 + lane;
            pr = src[n2]; pg = src[N_PIX + n2]; pb = src[2 * N_PIX + n2];
        }

#pragma unroll
        for (int h = 0; h < 2; ++h) {              // two K=32 halves
            const int base = h * 32 + quad * 8;    // first pixel this lane consumes
            const float4* __restrict__ pbase =
                (const float4*)(wbuf + base * 4 + (base >> 3) * 4);
            int aU[4][4], aV[4][4];                // fragment words [mt][jp]

#pragma unroll
            for (int jp = 0; jp < 4; ++jp) {       // j = 2jp (even), 2jp+1 (odd)
                const float4 pe = pbase[2 * jp];
                const float4 po = pbase[2 * jp + 1];

                f2 aue01, aue23, auo01, auo23;
                f2 bve01, bve23, bvo01, bvo23;
#pragma unroll
                for (int eo = 0; eo < 2; ++eo) {
                    const float ru = eo ? po.x : pe.x;
                    const float rv = eo ? po.y : pe.y;
                    const float rw = eo ? po.z : pe.z;
                    const f2 ru2 = {ru, ru}, rv2 = {rv, rv}, rw2 = {rw, rw};
                    const f2 tu01 = ru2 + ncb01, tu23 = ru2 + ncb23;
                    const f2 tv01 = rv2 + ncb01, tv23 = rv2 + ncb23;
                    const f2 qu01 = __builtin_elementwise_fma(tu01, tu01, one2);
                    const f2 qu23 = __builtin_elementwise_fma(tu23, tu23, one2);
                    const f2 qv01 = __builtin_elementwise_fma(tv01, tv01, one2);
                    const f2 qv23 = __builtin_elementwise_fma(tv23, tv23, one2);
                    // one rcp per denominator: trans pipe co-issues with VALU;
                    // V needs ZERO multiplies (rcp is the value), U just *w.
                    const f2 au01 = (f2){rcp_fast(qu01.x), rcp_fast(qu01.y)} * rw2;
                    const f2 au23 = (f2){rcp_fast(qu23.x), rcp_fast(qu23.y)} * rw2;
                    const f2 bv01 = {rcp_fast(qv01.x), rcp_fast(qv01.y)};
                    const f2 bv23 = {rcp_fast(qv23.x), rcp_fast(qv23.y)};
                    if (eo) { auo01 = au01; auo23 = au23; bvo01 = bv01; bvo23 = bv23; }
                    else    { aue01 = au01; aue23 = au23; bve01 = bv01; bve23 = bv23; }
                }
                aU[0][jp] = pk_bf16(aue01.x, auo01.x);   // mt0 <- center c0
                aU[1][jp] = pk_bf16(aue01.y, auo01.y);   // mt1 <- c1
                aU[2][jp] = pk_bf16(aue23.x, auo23.x);   // mt2 <- c2
                aU[3][jp] = pk_bf16(aue23.y, auo23.y);   // mt3 <- c3
                aV[0][jp] = pk_bf16(bve01.x, bvo01.x);
                aV[1][jp] = pk_bf16(bve01.y, bvo01.y);
                aV[2][jp] = pk_bf16(bve23.x, bvo23.x);
                aV[3][jp] = pk_bf16(bve23.y, bvo23.y);
            }

            short8 af[4], bf[4];
#pragma unroll
            for (int mt = 0; mt < 4; ++mt) {
                af[mt] = __builtin_bit_cast(short8,
                    make_int4(aU[mt][0], aU[mt][1], aU[mt][2], aU[mt][3]));
                bf[mt] = __builtin_bit_cast(short8,
                    make_int4(aV[mt][0], aV[mt][1], aV[mt][2], aV[mt][3]));
            }
#pragma unroll
            for (int mt = 0; mt < 4; ++mt)
#pragma unroll
                for (int nt = 0; nt < 4; ++nt)
                    acc[mt * 4 + nt] = __builtin_amdgcn_mfma_f32_16x16x32_bf16(
                        af[mt], bf[nt], acc[mt * 4 + nt], 0, 0, 0);
        }
    }

    // ---- Atomic-free epilogue: 4 chunks over mt; ALL traffic linear b128 ----
    float* __restrict__ outp = partial + (size_t)blk * 4096;
#pragma unroll 1
    for (int ch = 0; ch < 4; ++ch) {
        __syncthreads();                   // previous chunk (or main loop) done
#pragma unroll
        for (int nt = 0; nt < 4; ++nt)     // wave strip: [wv][nt*256 + lane*4 + i]
            *(f32x4*)(lds + wv * 1024 + nt * 256 + lane * 4) = acc[ch * 4 + nt];
        __syncthreads();
        const int e4 = tid * 4;            // 0..1023, linear -> conflict-free b128
        const f32x4 s0 = *(const f32x4*)(lds +        e4);
        const f32x4 s1 = *(const f32x4*)(lds + 1024 + e4);
        const f32x4 s2 = *(const f32x4*)(lds + 2048 + e4);
        const f32x4 s3 = *(const f32x4*)(lds + 3072 + e4);
        const f32x4 s = (s0 + s1) + (s2 + s3);
        // contiguous f32x4 store in wave-strip element order (no permutation;
        // bin mapping is job-independent so element e is consistent x vs y)
        *(f32x4*)(outp + ch * 1024 + e4) = s;
    }
}

// ---------------------------------------------------------------------------
// Kernel 2 (R6): Bhattacharyya-factored reduction + fused finalize — R0
// machinery, now over 16 chunks (12.6 MB partials; 32 f32x4 loads/thread,
// fully coalesced across lanes, bytes-in-flight per instr unchanged — the
// R3 scalar-load failure mode avoided by construction).
//   sum (sqrt(y/TY)-sqrt(x/TX))^2 = 2(1 - rho), rho = sum sqrt(sx*sy)/sqrt(TX*TY)
// 96 blocks x 256 (24 x-jobs x 4 slices): each thread owns one element-QUAD;
// accumulates qx, qy over the 16 chunk-partials with contiguous f32x4 loads,
// then sx=Σqx, sy=Σqy, cr=Σ sqrt(qx*qy). Block-reduce 3 scalars, 3 device
// atomicAdds; tid0 RELEASE-ticket; the 96th block ACQUIRE-loads accum and
// writes out[0].
// ---------------------------------------------------------------------------
__global__ __launch_bounds__(256) void reduce_cross_kernel(
    const float* __restrict__ partial, float* __restrict__ accum,
    float* __restrict__ out)
{
    unsigned* __restrict__ ticket = (unsigned*)(accum + 24);
    const int jx = blockIdx.x >> 2;                        // 0..23 (img0 job)
    const int bb = jx / 3;                                 // batch 0..7
    const int e4 = (((blockIdx.x & 3) << 8) | threadIdx.x) * 4;  // 0..4092
    const float* px = partial + (size_t)jx * CHUNKS * 4096 + e4;
    const float* py = partial + (size_t)(24 + jx) * CHUNKS * 4096 + e4;

    f32x4 qx = {0.f, 0.f, 0.f, 0.f}, qy = {0.f, 0.f, 0.f, 0.f};
#pragma unroll 8
    for (int k = 0; k < CHUNKS; ++k) {
        qx += *(const f32x4*)(px + (size_t)k * 4096);
        qy += *(const f32x4*)(py + (size_t)k * 4096);
    }
    float sx = (qx.x + qx.y) + (qx.z + qx.w);
    float sy = (qy.x + qy.y) + (qy.z + qy.w);
    float cr = (sqrtf(qx.x * qy.x) + sqrtf(qx.y * qy.y)) +
               (sqrtf(qx.z * qy.z) + sqrtf(qx.w * qy.w));

#pragma unroll
    for (int o = 32; o > 0; o >>= 1) {
        sx += __shfl_down(sx, o, 64);
        sy += __shfl_down(sy, o, 64);
        cr += __shfl_down(cr, o, 64);
    }
    __shared__ float red[12];
    const int wv = threadIdx.x >> 6;
    if ((threadIdx.x & 63) == 0) {
        red[wv] = sx; red[4 + wv] = sy; red[8 + wv] = cr;
    }
    __syncthreads();
    if (threadIdx.x == 0) {
        atomicAdd(&accum[bb],      red[0] + red[1] + red[2] + red[3]);
        atomicAdd(&accum[8 + bb],  red[4] + red[5] + red[6] + red[7]);
        atomicAdd(&accum[16 + bb], red[8] + red[9] + red[10] + red[11]);
        const unsigned old = __hip_atomic_fetch_add(ticket, 1u,
                                 __ATOMIC_ACQ_REL, __HIP_MEMORY_SCOPE_AGENT);
        if (old == N_RBLOCKS - 1) {        // last arriver: all atomicAdds visible
            float s = 0.0f;
#pragma unroll
            for (int b = 0; b < 8; ++b) {
                const float tx = __hip_atomic_load(&accum[b],      __ATOMIC_ACQUIRE, __HIP_MEMORY_SCOPE_AGENT);
                const float ty = __hip_atomic_load(&accum[8 + b],  __ATOMIC_ACQUIRE, __HIP_MEMORY_SCOPE_AGENT);
                const float cc = __hip_atomic_load(&accum[16 + b], __ATOMIC_ACQUIRE, __HIP_MEMORY_SCOPE_AGENT);
                const float rho = cc * __builtin_amdgcn_rsqf(tx * ty);
                s += sqrtf(fmaxf(1.0f - rho, 0.0f));
            }
            out[0] = s * 0.125f;
        }
    }
}

extern "C" void kernel_launch(void* const* d_in, const int* in_sizes, int n_in,
                              void* d_out, int out_size, void* d_ws, size_t ws_size,
                              hipStream_t stream)
{
    const float* x = (const float*)d_in[0];
    const float* y = (const float*)d_in[1];
    float* ws = (float*)d_ws;
    float* partial = ws;                                  // 768*4096 floats (12.6 MB)
    float* accum = ws + (size_t)N_BLOCKS * 4096;          // 24 floats + ticket
    float* outf = (float*)d_out;

    hipLaunchKernelGGL(hist_kernel, dim3(N_BLOCKS), dim3(256), 0, stream,
                       x, y, partial, accum);
    hipLaunchKernelGGL(reduce_cross_kernel, dim3(N_RBLOCKS), dim3(256), 0, stream,
                       partial, accum, outf);
}

// Round 7
// 149.926 us; speedup vs baseline: 1.5526x; 1.0159x over previous
//
#include <hip/hip_runtime.h>
#include <math.h>

#define N_PIX 65536
#define EPSF 1e-6f
#define CHUNKS 32
#define PX_PER_CHUNK 2048   // 65536 / 32
#define PX_PER_WAVE 512     // 4 waves per block, 8 super-tiles of 64 px
#define N_TILES (PX_PER_WAVE / 64)
#define N_JOBS 48           // 2 imgs * 8 batch * 3 channels
#define N_BLOCKS (N_JOBS * CHUNKS)   // 1536
#define N_RBLOCKS (24 * 4)           // 96 reduce blocks (f32x4 per thread)
#define LN2_50 34.65735903f // 50 * ln(2): log2 -> scaled-ln

typedef __attribute__((ext_vector_type(2))) float f2;
using short8 = __attribute__((ext_vector_type(8))) short;
using f32x4  = __attribute__((ext_vector_type(4))) float;

__device__ __forceinline__ float rcp_fast(float x) { return __builtin_amdgcn_rcpf(x); }

#if __has_builtin(__builtin_amdgcn_cvt_pk_bf16_f32)
typedef __attribute__((ext_vector_type(2))) __bf16 bf16x2_t;
__device__ __forceinline__ uint32_t pk_bf16(float a, float b) {
    return __builtin_bit_cast(uint32_t, __builtin_amdgcn_cvt_pk_bf16_f32(a, b));
}
#else
// fallback: round-half-up (inputs positive finite), 3 ops
__device__ __forceinline__ uint32_t pk_bf16(float a, float b) {
    const uint32_t ua = __builtin_bit_cast(uint32_t, a) + 0x8000u;
    const uint32_t ub = __builtin_bit_cast(uint32_t, b) + 0x8000u;
    return __builtin_amdgcn_perm(ub, ua, 0x07060302u);
}
#endif

// phase A: pixel -> (u*50, v*50, weight); log2-based (ln2 folded into scale)
__device__ __forceinline__ float4 phaseA(float pr, float pg, float pb, int c) {
    const float r  = pr + EPSF;
    const float g  = pg + EPSF;
    const float bl = pb + EPSF;
    const float wgt = sqrtf(fmaf(r, r, fmaf(g, g, bl * bl)));
    const float lr = __log2f(r), lg = __log2f(g), lb2 = __log2f(bl);
    // channel c: u = l_c - l_a, v = l_c - l_b;  c0:(a,b)=(g,b) c1:(r,b) c2:(r,g)
    const float l0 = (c == 0) ? lr : ((c == 1) ? lg : lb2);
    const float lu = (c == 0) ? lg : lr;
    const float lv = (c == 2) ? lg : lb2;
    return make_float4((l0 - lu) * LN2_50, (l0 - lv) * LN2_50, wgt, 0.0f);
}

// ---------------------------------------------------------------------------
// Kernel 1 (R7): R0/R19 structure restored VERBATIM (proven 148.4/149.2us
// total, hist 89us) with ONE single-token change: the super-tile loop is
// "#pragma unroll 2" (was 1). Rationale: in-order issue means the wave
// stalls at the first instruction dependent on a long-latency chain
// (rcp/log2/sqrt on the quarter-rate trans pipe); with unroll 1 the
// compiler cannot interleave tile t+1's independent phase-A chain into
// tile t's stalls. Unroll 2 permits exactly that cross-tile software
// pipelining without any barrier or structure change. wbuf aliasing (same
// LDS pointer in both sub-bodies) forces the compiler to keep t+1's
// ds_write ordered after t's ds_reads -> correctness preserved.
// LEDGER: gap(total-hist) = 54-60us regardless of k2 config (R0 32-chunk,
// R2, R6 16-chunk) => gap is fixed launch/drain/harness overhead; k2 is
// CLOSED. Atomic epilogues (R4 acq_rel, R5 plain f32) are chip-wide cache
// hazards: REVERTED forever. Block-barrier fragment sharing (R2): -12%
// despite +33% occupancy: barrier-free wave-private phases ARE the
// latency-hiding. Chunk rebalance 32->16 (R6): -5% (occupancy 21.6 vs
// 32.6). Phase-B eval: one v_rcp per denominator, fully-packed f2 ops.
// Contiguous b128 partial stores (wave-strip element order, job-independent
// bijection => elementwise k2 reduce exact). Block 0 zeroes accum+ticket.
// ---------------------------------------------------------------------------
__global__ __launch_bounds__(256, 4) void hist_kernel(
    const float* __restrict__ x, const float* __restrict__ y,
    float* __restrict__ partial, float* __restrict__ accum)
{
    const int blk = blockIdx.x;            // 0..1535
    const int chunk = blk & (CHUNKS - 1);
    const int job = blk / CHUNKS;          // 0..47
    const int c = job % 3;
    const int ib = job / 3;                // img*8 + b
    const int img = ib >> 3;
    const int b = ib & 7;
    const float* __restrict__ src = (img == 0 ? x : y) + (size_t)b * 3 * N_PIX;

    const int tid = threadIdx.x;
    if (blk == 0 && tid < 25) ((unsigned*)accum)[tid] = 0u;  // accum[24] + ticket

    __shared__ __align__(16) float lds[4096];   // 16 KB: wbufs / epilogue strips
    const int lane = tid & 63;
    const int wv = tid >> 6;
    float* __restrict__ wbuf = lds + wv * 288;  // 64 px * float4, +16B pad per 8 px

    const int quad = lane >> 4;
    const int l15 = lane & 15;
    // negated scaled centers for this lane's 4 m-rows: -(c_m * 50), m = mt*16+l15
    f2 ncb01, ncb23;
    {
        const float c0 = (-3.0f + (float)(l15)      * (6.0f / 63.0f)) * 50.0f;
        const float c1 = (-3.0f + (float)(16 + l15) * (6.0f / 63.0f)) * 50.0f;
        const float c2 = (-3.0f + (float)(32 + l15) * (6.0f / 63.0f)) * 50.0f;
        const float c3 = (-3.0f + (float)(48 + l15) * (6.0f / 63.0f)) * 50.0f;
        ncb01 = (f2){-c0, -c1};
        ncb23 = (f2){-c2, -c3};
    }
    const f2 one2 = {1.0f, 1.0f};

    f32x4 acc[16];                         // acc[mt*4+nt]
#pragma unroll
    for (int i = 0; i < 16; ++i) acc[i] = (f32x4){0.f, 0.f, 0.f, 0.f};

    const int px0 = chunk * PX_PER_CHUNK + wv * PX_PER_WAVE;

    // prefetch super-tile 0
    float pr, pg, pb;
    {
        const int n = px0 + lane;
        pr = src[n]; pg = src[N_PIX + n]; pb = src[2 * N_PIX + n];
    }

#pragma unroll 2
    for (int st = 0; st < N_TILES; ++st) {
        // ---- Phase A: one pixel per lane; stage to LDS (same-wave, in-order) ----
        const float4 uvw = phaseA(pr, pg, pb, c);
        *(float4*)(wbuf + lane * 4 + (lane >> 3) * 4) = uvw;

        if (st + 1 < N_TILES) {            // prefetch next tile's raw pixels
            const int n2 = px0 + (st + 1) * 64 + lane;
            pr = src[n2]; pg = src[N_PIX + n2]; pb = src[2 * N_PIX + n2];
        }

#pragma unroll
        for (int h = 0; h < 2; ++h) {              // two K=32 halves
            const int base = h * 32 + quad * 8;    // first pixel this lane consumes
            const float4* __restrict__ pbase =
                (const float4*)(wbuf + base * 4 + (base >> 3) * 4);
            int aU[4][4], aV[4][4];                // fragment words [mt][jp]

#pragma unroll
            for (int jp = 0; jp < 4; ++jp) {       // j = 2jp (even), 2jp+1 (odd)
                const float4 pe = pbase[2 * jp];
                const float4 po = pbase[2 * jp + 1];

                f2 aue01, aue23, auo01, auo23;
                f2 bve01, bve23, bvo01, bvo23;
#pragma unroll
                for (int eo = 0; eo < 2; ++eo) {
                    const float ru = eo ? po.x : pe.x;
                    const float rv = eo ? po.y : pe.y;
                    const float rw = eo ? po.z : pe.z;
                    const f2 ru2 = {ru, ru}, rv2 = {rv, rv}, rw2 = {rw, rw};
                    const f2 tu01 = ru2 + ncb01, tu23 = ru2 + ncb23;
                    const f2 tv01 = rv2 + ncb01, tv23 = rv2 + ncb23;
                    const f2 qu01 = __builtin_elementwise_fma(tu01, tu01, one2);
                    const f2 qu23 = __builtin_elementwise_fma(tu23, tu23, one2);
                    const f2 qv01 = __builtin_elementwise_fma(tv01, tv01, one2);
                    const f2 qv23 = __builtin_elementwise_fma(tv23, tv23, one2);
                    // one rcp per denominator: trans pipe co-issues with VALU;
                    // V needs ZERO multiplies (rcp is the value), U just *w.
                    const f2 au01 = (f2){rcp_fast(qu01.x), rcp_fast(qu01.y)} * rw2;
                    const f2 au23 = (f2){rcp_fast(qu23.x), rcp_fast(qu23.y)} * rw2;
                    const f2 bv01 = {rcp_fast(qv01.x), rcp_fast(qv01.y)};
                    const f2 bv23 = {rcp_fast(qv23.x), rcp_fast(qv23.y)};
                    if (eo) { auo01 = au01; auo23 = au23; bvo01 = bv01; bvo23 = bv23; }
                    else    { aue01 = au01; aue23 = au23; bve01 = bv01; bve23 = bv23; }
                }
                aU[0][jp] = pk_bf16(aue01.x, auo01.x);   // mt0 <- center c0
                aU[1][jp] = pk_bf16(aue01.y, auo01.y);   // mt1 <- c1
                aU[2][jp] = pk_bf16(aue23.x, auo23.x);   // mt2 <- c2
                aU[3][jp] = pk_bf16(aue23.y, auo23.y);   // mt3 <- c3
                aV[0][jp] = pk_bf16(bve01.x, bvo01.x);
                aV[1][jp] = pk_bf16(bve01.y, bvo01.y);
                aV[2][jp] = pk_bf16(bve23.x, bvo23.x);
                aV[3][jp] = pk_bf16(bve23.y, bvo23.y);
            }

            short8 af[4], bf[4];
#pragma unroll
            for (int mt = 0; mt < 4; ++mt) {
                af[mt] = __builtin_bit_cast(short8,
                    make_int4(aU[mt][0], aU[mt][1], aU[mt][2], aU[mt][3]));
                bf[mt] = __builtin_bit_cast(short8,
                    make_int4(aV[mt][0], aV[mt][1], aV[mt][2], aV[mt][3]));
            }
#pragma unroll
            for (int mt = 0; mt < 4; ++mt)
#pragma unroll
                for (int nt = 0; nt < 4; ++nt)
                    acc[mt * 4 + nt] = __builtin_amdgcn_mfma_f32_16x16x32_bf16(
                        af[mt], bf[nt], acc[mt * 4 + nt], 0, 0, 0);
        }
    }

    // ---- Atomic-free epilogue: 4 chunks over mt; ALL traffic linear b128 ----
    float* __restrict__ outp = partial + (size_t)blk * 4096;
#pragma unroll 1
    for (int ch = 0; ch < 4; ++ch) {
        __syncthreads();                   // previous chunk (or main loop) done
#pragma unroll
        for (int nt = 0; nt < 4; ++nt)     // wave strip: [wv][nt*256 + lane*4 + i]
            *(f32x4*)(lds + wv * 1024 + nt * 256 + lane * 4) = acc[ch * 4 + nt];
        __syncthreads();
        const int e4 = tid * 4;            // 0..1023, linear -> conflict-free b128
        const f32x4 s0 = *(const f32x4*)(lds +        e4);
        const f32x4 s1 = *(const f32x4*)(lds + 1024 + e4);
        const f32x4 s2 = *(const f32x4*)(lds + 2048 + e4);
        const f32x4 s3 = *(const f32x4*)(lds + 3072 + e4);
        const f32x4 s = (s0 + s1) + (s2 + s3);
        // contiguous f32x4 store in wave-strip element order (no permutation;
        // bin mapping is job-independent so element e is consistent x vs y)
        *(f32x4*)(outp + ch * 1024 + e4) = s;
    }
}

// ---------------------------------------------------------------------------
// Kernel 2 (R0 verbatim): Bhattacharyya-factored reduction + fused finalize.
//   sum (sqrt(y/TY)-sqrt(x/TX))^2 = 2(1 - rho), rho = sum sqrt(sx*sy)/sqrt(TX*TY)
// 96 blocks x 256 (24 x-jobs x 4 slices): each thread owns one element-QUAD;
// accumulates qx, qy over the 32 chunk-partials with contiguous f32x4 loads,
// then sx=Σqx, sy=Σqy, cr=Σ sqrt(qx*qy). Block-reduce 3 scalars, 3 device
// atomicAdds; tid0 RELEASE-ticket; the 96th block ACQUIRE-loads accum and
// writes out[0]. Gap(total-hist) proven insensitive to k2 work (R0/R2/R6):
// this kernel is NOT the bottleneck; do not touch it again.
// ---------------------------------------------------------------------------
__global__ __launch_bounds__(256) void reduce_cross_kernel(
    const float* __restrict__ partial, float* __restrict__ accum,
    float* __restrict__ out)
{
    unsigned* __restrict__ ticket = (unsigned*)(accum + 24);
    const int jx = blockIdx.x >> 2;                        // 0..23 (img0 job)
    const int bb = jx / 3;                                 // batch 0..7
    const int e4 = (((blockIdx.x & 3) << 8) | threadIdx.x) * 4;  // 0..4092
    const float* px = partial + (size_t)jx * CHUNKS * 4096 + e4;
    const float* py = partial + (size_t)(24 + jx) * CHUNKS * 4096 + e4;

    f32x4 qx = {0.f, 0.f, 0.f, 0.f}, qy = {0.f, 0.f, 0.f, 0.f};
#pragma unroll 8
    for (int k = 0; k < CHUNKS; ++k) {
        qx += *(const f32x4*)(px + (size_t)k * 4096);
        qy += *(const f32x4*)(py + (size_t)k * 4096);
    }
    float sx = (qx.x + qx.y) + (qx.z + qx.w);
    float sy = (qy.x + qy.y) + (qy.z + qy.w);
    float cr = (sqrtf(qx.x * qy.x) + sqrtf(qx.y * qy.y)) +
               (sqrtf(qx.z * qy.z) + sqrtf(qx.w * qy.w));

#pragma unroll
    for (int o = 32; o > 0; o >>= 1) {
        sx += __shfl_down(sx, o, 64);
        sy += __shfl_down(sy, o, 64);
        cr += __shfl_down(cr, o, 64);
    }
    __shared__ float red[12];
    const int wv = threadIdx.x >> 6;
    if ((threadIdx.x & 63) == 0) {
        red[wv] = sx; red[4 + wv] = sy; red[8 + wv] = cr;
    }
    __syncthreads();
    if (threadIdx.x == 0) {
        atomicAdd(&accum[bb],      red[0] + red[1] + red[2] + red[3]);
        atomicAdd(&accum[8 + bb],  red[4] + red[5] + red[6] + red[7]);
        atomicAdd(&accum[16 + bb], red[8] + red[9] + red[10] + red[11]);
        const unsigned old = __hip_atomic_fetch_add(ticket, 1u,
                                 __ATOMIC_ACQ_REL, __HIP_MEMORY_SCOPE_AGENT);
        if (old == N_RBLOCKS - 1) {        // last arriver: all atomicAdds visible
            float s = 0.0f;
#pragma unroll
            for (int b = 0; b < 8; ++b) {
                const float tx = __hip_atomic_load(&accum[b],      __ATOMIC_ACQUIRE, __HIP_MEMORY_SCOPE_AGENT);
                const float ty = __hip_atomic_load(&accum[8 + b],  __ATOMIC_ACQUIRE, __HIP_MEMORY_SCOPE_AGENT);
                const float cc = __hip_atomic_load(&accum[16 + b], __ATOMIC_ACQUIRE, __HIP_MEMORY_SCOPE_AGENT);
                const float rho = cc * __builtin_amdgcn_rsqf(tx * ty);
                s += sqrtf(fmaxf(1.0f - rho, 0.0f));
            }
            out[0] = s * 0.125f;
        }
    }
}

extern "C" void kernel_launch(void* const* d_in, const int* in_sizes, int n_in,
                              void* d_out, int out_size, void* d_ws, size_t ws_size,
                              hipStream_t stream)
{
    const float* x = (const float*)d_in[0];
    const float* y = (const float*)d_in[1];
    float* ws = (float*)d_ws;
    float* partial = ws;                                  // 1536*4096 floats (25.2 MB)
    float* accum = ws + (size_t)N_BLOCKS * 4096;          // 24 floats + ticket
    float* outf = (float*)d_out;

    hipLaunchKernelGGL(hist_kernel, dim3(N_BLOCKS), dim3(256), 0, stream,
                       x, y, partial, accum);
    hipLaunchKernelGGL(reduce_cross_kernel, dim3(N_RBLOCKS), dim3(256), 0, stream,
                       partial, accum, outf);
}